// Round 1
// baseline (93.711 us; speedup 1.0000x reference)
//
#include <hip/hip_runtime.h>
#include <hip/hip_fp16.h>

typedef _Float16 half_t;
typedef _Float16 f16x8 __attribute__((ext_vector_type(8)));
typedef float f32x4 __attribute__((ext_vector_type(4)));

#define MFMA_F16(a, b, c) __builtin_amdgcn_mfma_f32_16x16x32_f16((a), (b), (c), 0, 0, 0)

// ---------------------------------------------------------------------------
// transpose + fp32->fp16 convert:  out[c][r] = (half) in[r][c],  in is R x C
// ---------------------------------------------------------------------------
__global__ void transpose_cvt(const float* __restrict__ in, half_t* __restrict__ out,
                              int R, int C) {
    int idx = blockIdx.x * 256 + threadIdx.x;
    if (idx >= R * C) return;
    int r = idx / C, c = idx - r * C;
    out[c * R + r] = (half_t)in[idx];
}

// ---------------------------------------------------------------------------
// Generic fp16 MFMA GEMM:  D[M][N] = A[M][K] * Bt[N][K]^T
// BM=64, BN=256, BK=64, 256 threads (4 waves, 2x2), wave tile 32x128.
// EPI 0: store half_t row-major ld=256 (xr)
// EPI 1: scatter to qkv [3][B][H][NB][256][32] half_t
// EPI 2: float out[grow*512+gcol] = acc + bias[gcol]
// ---------------------------------------------------------------------------
template <int EPI, bool AFP32>
__global__ __launch_bounds__(256) void gemm_f16(
    const void* __restrict__ Aptr, const half_t* __restrict__ Bt,
    void* __restrict__ Dst, const float* __restrict__ bias, int K) {
    __shared__ __align__(16) char smem[(64 + 256) * 64 * 2];  // As 8KB + Bs 32KB
    char* As = smem;
    char* Bs = smem + 64 * 64 * 2;

    const int tid = threadIdx.x;
    const int lane = tid & 63, w = tid >> 6;
    const int l15 = lane & 15, l4 = lane >> 4;
    const int wrow = (w >> 1) * 32, wcol = (w & 1) * 128;
    const int bm0 = blockIdx.x * 64;
    const int bn0 = blockIdx.y * 256;

    f32x4 acc[2][8];
#pragma unroll
    for (int i = 0; i < 2; ++i)
#pragma unroll
        for (int j = 0; j < 8; ++j) acc[i][j] = (f32x4){0.f, 0.f, 0.f, 0.f};

    const int nkt = K >> 6;
    for (int kt = 0; kt < nkt; ++kt) {
        __syncthreads();
        // ---- stage A (64x64 halves = 512 chunks of 8) ----
#pragma unroll
        for (int i = 0; i < 2; ++i) {
            int c = tid + i * 256;
            int row = c >> 3, k0 = (c & 7) * 8;
            int gk = kt * 64 + k0;
            f16x8 v;
            if (AFP32) {
                const float* Af = (const float*)Aptr + (size_t)(bm0 + row) * K + gk;
                float4 u0 = *(const float4*)Af;
                float4 u1 = *(const float4*)(Af + 4);
                v[0] = (half_t)u0.x; v[1] = (half_t)u0.y;
                v[2] = (half_t)u0.z; v[3] = (half_t)u0.w;
                v[4] = (half_t)u1.x; v[5] = (half_t)u1.y;
                v[6] = (half_t)u1.z; v[7] = (half_t)u1.w;
            } else {
                v = *(const f16x8*)((const half_t*)Aptr + (size_t)(bm0 + row) * K + gk);
            }
            *(f16x8*)(As + row * 128 + ((k0 * 2) ^ ((row & 7) << 4))) = v;
        }
        // ---- stage B (256x64 halves = 2048 chunks of 8) ----
#pragma unroll
        for (int i = 0; i < 8; ++i) {
            int c = tid + i * 256;
            int row = c >> 3, k0 = (c & 7) * 8;
            int gk = kt * 64 + k0;
            f16x8 v = *(const f16x8*)(Bt + (size_t)(bn0 + row) * K + gk);
            *(f16x8*)(Bs + row * 128 + ((k0 * 2) ^ ((row & 7) << 4))) = v;
        }
        __syncthreads();
        // ---- compute ----
#pragma unroll
        for (int ki = 0; ki < 2; ++ki) {
            int k0 = ki * 32 + l4 * 8;
            f16x8 af[2], bfr[8];
#pragma unroll
            for (int mi = 0; mi < 2; ++mi) {
                int row = wrow + mi * 16 + l15;
                af[mi] = *(const f16x8*)(As + row * 128 + ((k0 * 2) ^ ((row & 7) << 4)));
            }
#pragma unroll
            for (int nj = 0; nj < 8; ++nj) {
                int row = wcol + nj * 16 + l15;
                bfr[nj] = *(const f16x8*)(Bs + row * 128 + ((k0 * 2) ^ ((row & 7) << 4)));
            }
#pragma unroll
            for (int mi = 0; mi < 2; ++mi)
#pragma unroll
                for (int nj = 0; nj < 8; ++nj)
                    acc[mi][nj] = MFMA_F16(af[mi], bfr[nj], acc[mi][nj]);
        }
    }

    // ---- epilogue ----
#pragma unroll
    for (int mi = 0; mi < 2; ++mi) {
#pragma unroll
        for (int nj = 0; nj < 8; ++nj) {
#pragma unroll
            for (int reg = 0; reg < 4; ++reg) {
                int grow = bm0 + wrow + mi * 16 + l4 * 4 + reg;
                int gcol = bn0 + wcol + nj * 16 + l15;
                float val = acc[mi][nj][reg];
                if (EPI == 0) {
                    ((half_t*)Dst)[(size_t)grow * 256 + gcol] = (half_t)val;
                } else if (EPI == 1) {
                    int t = gcol >> 8, h = (gcol >> 5) & 7, dd = gcol & 31;
                    int b = grow >> 12, n = grow & 4095;
                    int blk = n >> 8, r = n & 255;
                    size_t idx = (size_t)t * 4194304 +
                                 (size_t)((((b << 3) + h) << 4) + blk) * 8192 +
                                 (size_t)r * 32 + dd;
                    ((half_t*)Dst)[idx] = (half_t)val;
                } else {
                    ((float*)Dst)[(size_t)grow * 512 + gcol] = val + bias[gcol];
                }
            }
        }
    }
}

// ---------------------------------------------------------------------------
// Block-diagonal attention. One WG per (b,h,blk): 256 q rows, 256 keys, d=32.
// 4 waves, each owns 64 q rows. K/Q frags straight from global (L2-hot),
// V transposed into LDS, P staged per-wave in LDS, online softmax.
// ---------------------------------------------------------------------------
__global__ __launch_bounds__(256) void attn_f16(const half_t* __restrict__ qkv_ws,
                                                half_t* __restrict__ o_ws) {
    __shared__ __align__(16) half_t VT[32 * 264];    // V^T [d][key], padded
    __shared__ __align__(16) half_t Ps[4][64 * 72];  // per-wave P tile [q][key]

    const int bid = blockIdx.x;  // (b*8+h)*16+blk
    const int b = bid >> 7, h = (bid >> 4) & 7, blk = bid & 15;
    const half_t* Q = qkv_ws + (size_t)bid * 8192;
    const half_t* Kp = qkv_ws + 4194304 + (size_t)bid * 8192;
    const half_t* V = qkv_ws + 8388608 + (size_t)bid * 8192;

    const int tid = threadIdx.x, lane = tid & 63, w = tid >> 6;
    const int l15 = lane & 15, l4 = lane >> 4;

    // build V^T in LDS
#pragma unroll
    for (int i = 0; i < 4; ++i) {
        int c = tid + i * 256;
        int key = c >> 2, k8 = (c & 3) * 8;
        f16x8 v = *(const f16x8*)(V + key * 32 + k8);
#pragma unroll
        for (int e = 0; e < 8; ++e) VT[(k8 + e) * 264 + key] = v[e];
    }

    // Q fragments (rows w*64 .. +63), fold in softmax scale (exact pow2)
    f16x8 aq[4];
#pragma unroll
    for (int fi = 0; fi < 4; ++fi) {
        f16x8 v = *(const f16x8*)(Q + (w * 64 + fi * 16 + l15) * 32 + l4 * 8);
        aq[fi] = v * (half_t)0.125f;
    }

    __syncthreads();

    float m_run[4][4], s_run[4][4];
    f32x4 acc_o[4][2];
#pragma unroll
    for (int fi = 0; fi < 4; ++fi)
#pragma unroll
        for (int r = 0; r < 4; ++r) { m_run[fi][r] = -1e30f; s_run[fi][r] = 0.f; }
#pragma unroll
    for (int fi = 0; fi < 4; ++fi)
#pragma unroll
        for (int fo = 0; fo < 2; ++fo) acc_o[fi][fo] = (f32x4){0.f, 0.f, 0.f, 0.f};

    const f32x4 zero4 = (f32x4){0.f, 0.f, 0.f, 0.f};

    for (int kt = 0; kt < 4; ++kt) {
        // K fragments from global (B-operand of QK^T)
        f16x8 bk[4];
#pragma unroll
        for (int fj = 0; fj < 4; ++fj)
            bk[fj] = *(const f16x8*)(Kp + (kt * 64 + fj * 16 + l15) * 32 + l4 * 8);

        // S = (Q*scale) K^T : 16 MFMAs, K-dim=32 in one shot
        f32x4 s_[4][4];
#pragma unroll
        for (int fi = 0; fi < 4; ++fi)
#pragma unroll
            for (int fj = 0; fj < 4; ++fj) s_[fi][fj] = MFMA_F16(aq[fi], bk[fj], zero4);

        // row max of tile (over fj in-lane, then over 16-lane col groups)
        float mt[4][4];
#pragma unroll
        for (int fi = 0; fi < 4; ++fi)
#pragma unroll
            for (int r = 0; r < 4; ++r)
                mt[fi][r] = fmaxf(fmaxf(s_[fi][0][r], s_[fi][1][r]),
                                  fmaxf(s_[fi][2][r], s_[fi][3][r]));
#pragma unroll
        for (int m = 1; m <= 8; m <<= 1)
#pragma unroll
            for (int fi = 0; fi < 4; ++fi)
#pragma unroll
                for (int r = 0; r < 4; ++r)
                    mt[fi][r] = fmaxf(mt[fi][r], __shfl_xor(mt[fi][r], m));

        // online-softmax update
        float corr_a[4][4], psum[4][4];
#pragma unroll
        for (int fi = 0; fi < 4; ++fi)
#pragma unroll
            for (int r = 0; r < 4; ++r) {
                float mn = fmaxf(m_run[fi][r], mt[fi][r]);
                corr_a[fi][r] = __expf(m_run[fi][r] - mn);
                m_run[fi][r] = mn;
                float ps = 0.f;
#pragma unroll
                for (int fj = 0; fj < 4; ++fj) {
                    float p = __expf(s_[fi][fj][r] - mn);
                    s_[fi][fj][r] = p;
                    ps += p;
                }
                psum[fi][r] = ps;
            }
#pragma unroll
        for (int m = 1; m <= 8; m <<= 1)
#pragma unroll
            for (int fi = 0; fi < 4; ++fi)
#pragma unroll
                for (int r = 0; r < 4; ++r) psum[fi][r] += __shfl_xor(psum[fi][r], m);
#pragma unroll
        for (int fi = 0; fi < 4; ++fi)
#pragma unroll
            for (int r = 0; r < 4; ++r)
                s_run[fi][r] = s_run[fi][r] * corr_a[fi][r] + psum[fi][r];
#pragma unroll
        for (int fi = 0; fi < 4; ++fi)
#pragma unroll
            for (int fo = 0; fo < 2; ++fo)
#pragma unroll
                for (int r = 0; r < 4; ++r) acc_o[fi][fo][r] *= corr_a[fi][r];

        // write P (fp16) to this wave's LDS tile
#pragma unroll
        for (int fi = 0; fi < 4; ++fi)
#pragma unroll
            for (int fj = 0; fj < 4; ++fj)
#pragma unroll
                for (int r = 0; r < 4; ++r)
                    Ps[w][(fi * 16 + l4 * 4 + r) * 72 + fj * 16 + l15] =
                        (half_t)s_[fi][fj][r];

        // O += P V  (K-dim 64 -> two MFMA steps)
#pragma unroll
        for (int ki = 0; ki < 2; ++ki) {
            f16x8 ap[4], bv[2];
#pragma unroll
            for (int fi = 0; fi < 4; ++fi)
                ap[fi] = *(const f16x8*)&Ps[w][(fi * 16 + l15) * 72 + ki * 32 + l4 * 8];
#pragma unroll
            for (int fo = 0; fo < 2; ++fo)
                bv[fo] = *(const f16x8*)&VT[(fo * 16 + l15) * 264 + kt * 64 + ki * 32 + l4 * 8];
#pragma unroll
            for (int fi = 0; fi < 4; ++fi)
#pragma unroll
                for (int fo = 0; fo < 2; ++fo)
                    acc_o[fi][fo] = MFMA_F16(ap[fi], bv[fo], acc_o[fi][fo]);
        }
    }

    // finalize + store o (head-major layout [row][h*32+dd])
#pragma unroll
    for (int fi = 0; fi < 4; ++fi) {
        float inv[4];
#pragma unroll
        for (int r = 0; r < 4; ++r) inv[r] = 1.f / s_run[fi][r];
#pragma unroll
        for (int fo = 0; fo < 2; ++fo)
#pragma unroll
            for (int r = 0; r < 4; ++r) {
                int grow = b * 4096 + blk * 256 + w * 64 + fi * 16 + l4 * 4 + r;
                o_ws[(size_t)grow * 256 + h * 32 + fo * 16 + l15] =
                    (half_t)(acc_o[fi][fo][r] * inv[r]);
            }
    }
}

// ---------------------------------------------------------------------------
extern "C" void kernel_launch(void* const* d_in, const int* in_sizes, int n_in,
                              void* d_out, int out_size, void* d_ws, size_t ws_size,
                              hipStream_t stream) {
    const float* x        = (const float*)d_in[0];
    const float* reduce_w = (const float*)d_in[1];
    const float* qkv_w    = (const float*)d_in[2];
    const float* proj_w   = (const float*)d_in[3];
    const float* proj_b   = (const float*)d_in[4];
    char* ws = (char*)d_ws;

    // ws layout (bytes):
    //   qkv_ws : 0          .. 25,165,824   (3 x 4,194,304 halves, q/k/v)
    //   xro    : 25,165,824 .. 33,554,432   (xr, later reused as o)
    //   rw_t   : 33,554,432 (+262,144)
    //   qw_t   : 33,816,576 (+393,216)
    //   pw_t   : 34,209,792 (+262,144)
    half_t* qkv_ws = (half_t*)ws;
    half_t* xro    = (half_t*)(ws + 25165824);
    half_t* rw_t   = (half_t*)(ws + 33554432);
    half_t* qw_t   = (half_t*)(ws + 33816576);
    half_t* pw_t   = (half_t*)(ws + 34209792);

    transpose_cvt<<<512, 256, 0, stream>>>(reduce_w, rw_t, 512, 256);
    transpose_cvt<<<768, 256, 0, stream>>>(qkv_w,   qw_t, 256, 768);
    transpose_cvt<<<512, 256, 0, stream>>>(proj_w,  pw_t, 256, 512);

    // xr = x @ reduce_w         (M=16384, N=256, K=512), fp32 A
    gemm_f16<0, true ><<<dim3(256, 1), 256, 0, stream>>>(x,   rw_t, xro,    nullptr, 512);
    // qkv = xr @ qkv_w          (M=16384, N=768, K=256), scatter epilogue
    gemm_f16<1, false><<<dim3(256, 3), 256, 0, stream>>>(xro, qw_t, qkv_ws, nullptr, 256);
    // block-diagonal attention  (512 WGs), writes o into xro
    attn_f16<<<512, 256, 0, stream>>>(qkv_ws, xro);
    // out = o @ proj_w + proj_b (M=16384, N=512, K=256), fp32 out
    gemm_f16<2, false><<<dim3(256, 2), 256, 0, stream>>>(xro, pw_t, d_out,  proj_b, 256);
}

// Round 3
// 80.541 us; speedup vs baseline: 1.1635x; 1.1635x over previous
//
#include <hip/hip_runtime.h>
#include <hip/hip_fp16.h>

typedef _Float16 half_t;
typedef _Float16 f16x8 __attribute__((ext_vector_type(8)));
typedef __fp16 fp16x2 __attribute__((ext_vector_type(2)));
typedef float f32x4 __attribute__((ext_vector_type(4)));

#define MFMA_F16(a, b, c) __builtin_amdgcn_mfma_f32_16x16x32_f16((a), (b), (c), 0, 0, 0)

static __device__ inline unsigned pkrtz(float a, float b) {
    union { fp16x2 h; unsigned u; } c;
    c.h = __builtin_amdgcn_cvt_pkrtz(a, b);
    return c.u;
}

// ---------------------------------------------------------------------------
// transpose + fp32->fp16 convert:  out[c][r] = (half) in[r][c],  in is R x C
// ---------------------------------------------------------------------------
__global__ void transpose_cvt(const float* __restrict__ in, half_t* __restrict__ out,
                              int R, int C) {
    int idx = blockIdx.x * 256 + threadIdx.x;
    if (idx >= R * C) return;
    int r = idx / C, c = idx - r * C;
    out[c * R + r] = (half_t)in[idx];
}

// ---------------------------------------------------------------------------
// Generic fp16 MFMA GEMM:  D[M][N] = A[M][K] * Bt[N][K]^T
// BM=64, BN=256, BK=64, 256 threads (4 waves, 2x2), wave tile 32x128.
// EPI 0: store half_t row-major ld=256 (xr)
// EPI 1: scatter to qkv [3][B][H][NB][256][32] half_t
// EPI 2: float out[grow*512+gcol] = acc + bias[gcol]
// ---------------------------------------------------------------------------
template <int EPI, bool AFP32>
__global__ __launch_bounds__(256) void gemm_f16(
    const void* __restrict__ Aptr, const half_t* __restrict__ Bt,
    void* __restrict__ Dst, const float* __restrict__ bias, int K) {
    __shared__ __align__(16) char smem[(64 + 256) * 64 * 2];  // As 8KB + Bs 32KB
    char* As = smem;
    char* Bs = smem + 64 * 64 * 2;

    const int tid = threadIdx.x;
    const int lane = tid & 63, w = tid >> 6;
    const int l15 = lane & 15, l4 = lane >> 4;
    const int wrow = (w >> 1) * 32, wcol = (w & 1) * 128;
    const int bm0 = blockIdx.x * 64;
    const int bn0 = blockIdx.y * 256;

    f32x4 acc[2][8];
#pragma unroll
    for (int i = 0; i < 2; ++i)
#pragma unroll
        for (int j = 0; j < 8; ++j) acc[i][j] = (f32x4){0.f, 0.f, 0.f, 0.f};

    const int nkt = K >> 6;
    for (int kt = 0; kt < nkt; ++kt) {
        __syncthreads();
        // ---- stage A (64x64 halves = 512 chunks of 8) ----
#pragma unroll
        for (int i = 0; i < 2; ++i) {
            int c = tid + i * 256;
            int row = c >> 3, k0 = (c & 7) * 8;
            int gk = kt * 64 + k0;
            f16x8 v;
            if (AFP32) {
                const float* Af = (const float*)Aptr + (size_t)(bm0 + row) * K + gk;
                float4 u0 = *(const float4*)Af;
                float4 u1 = *(const float4*)(Af + 4);
                v[0] = (half_t)u0.x; v[1] = (half_t)u0.y;
                v[2] = (half_t)u0.z; v[3] = (half_t)u0.w;
                v[4] = (half_t)u1.x; v[5] = (half_t)u1.y;
                v[6] = (half_t)u1.z; v[7] = (half_t)u1.w;
            } else {
                v = *(const f16x8*)((const half_t*)Aptr + (size_t)(bm0 + row) * K + gk);
            }
            *(f16x8*)(As + row * 128 + ((k0 * 2) ^ ((row & 7) << 4))) = v;
        }
        // ---- stage B (256x64 halves = 2048 chunks of 8) ----
#pragma unroll
        for (int i = 0; i < 8; ++i) {
            int c = tid + i * 256;
            int row = c >> 3, k0 = (c & 7) * 8;
            int gk = kt * 64 + k0;
            f16x8 v = *(const f16x8*)(Bt + (size_t)(bn0 + row) * K + gk);
            *(f16x8*)(Bs + row * 128 + ((k0 * 2) ^ ((row & 7) << 4))) = v;
        }
        __syncthreads();
        // ---- compute ----
#pragma unroll
        for (int ki = 0; ki < 2; ++ki) {
            int k0 = ki * 32 + l4 * 8;
            f16x8 af[2], bfr[8];
#pragma unroll
            for (int mi = 0; mi < 2; ++mi) {
                int row = wrow + mi * 16 + l15;
                af[mi] = *(const f16x8*)(As + row * 128 + ((k0 * 2) ^ ((row & 7) << 4)));
            }
#pragma unroll
            for (int nj = 0; nj < 8; ++nj) {
                int row = wcol + nj * 16 + l15;
                bfr[nj] = *(const f16x8*)(Bs + row * 128 + ((k0 * 2) ^ ((row & 7) << 4)));
            }
#pragma unroll
            for (int mi = 0; mi < 2; ++mi)
#pragma unroll
                for (int nj = 0; nj < 8; ++nj)
                    acc[mi][nj] = MFMA_F16(af[mi], bfr[nj], acc[mi][nj]);
        }
    }

    // ---- epilogue ----
#pragma unroll
    for (int mi = 0; mi < 2; ++mi) {
#pragma unroll
        for (int nj = 0; nj < 8; ++nj) {
#pragma unroll
            for (int reg = 0; reg < 4; ++reg) {
                int grow = bm0 + wrow + mi * 16 + l4 * 4 + reg;
                int gcol = bn0 + wcol + nj * 16 + l15;
                float val = acc[mi][nj][reg];
                if (EPI == 0) {
                    ((half_t*)Dst)[(size_t)grow * 256 + gcol] = (half_t)val;
                } else if (EPI == 1) {
                    int t = gcol >> 8, h = (gcol >> 5) & 7, dd = gcol & 31;
                    int b = grow >> 12, n = grow & 4095;
                    int blk = n >> 8, r = n & 255;
                    size_t idx = (size_t)t * 4194304 +
                                 (size_t)((((b << 3) + h) << 4) + blk) * 8192 +
                                 (size_t)r * 32 + dd;
                    ((half_t*)Dst)[idx] = (half_t)val;
                } else {
                    ((float*)Dst)[(size_t)grow * 512 + gcol] = val + bias[gcol];
                }
            }
        }
    }
}

// ---------------------------------------------------------------------------
// Block-diagonal attention, swapped-QK^T layout.
// Grid 2048 = 512 blocks x 4 q-quadrants; WG = 256 threads (4 waves),
// each wave owns 16 q rows. S^T = mfma(K, Q): lane holds P for q = lane&15,
// k = 16t + (lane>>4)*4 + r  -> softmax reductions are in-lane + 2 shfl_xor.
// P repacked to PV A-frags via cvt_pkrtz + shfl (no P LDS). V^T in LDS.
// ---------------------------------------------------------------------------
__global__ __launch_bounds__(256, 4) void attn_f16(const half_t* __restrict__ qkv_ws,
                                                   half_t* __restrict__ o_ws) {
    __shared__ __align__(16) half_t VT[32 * 264];  // V^T [dd][key], stride 264

    const int bid = blockIdx.x;
    const int blkid = bid >> 2;       // (b*8+h)*16+blk
    const int qquad = bid & 3;
    const int b = blkid >> 7, h = (blkid >> 4) & 7, blk = blkid & 15;
    const half_t* Q = qkv_ws + (size_t)blkid * 8192;
    const half_t* Kp = qkv_ws + 4194304 + (size_t)blkid * 8192;
    const half_t* V = qkv_ws + 8388608 + (size_t)blkid * 8192;

    const int tid = threadIdx.x, lane = tid & 63, w = tid >> 6;
    const int l15 = lane & 15, l4 = lane >> 4;
    const int qb = qquad * 64 + w * 16;  // this wave's q-row base (16 rows)

    // build V^T in LDS (one-time; 8-way write conflict accepted)
#pragma unroll
    for (int i = 0; i < 4; ++i) {
        int c = tid + i * 256;
        int key = c >> 2, k8 = (c & 3) * 8;
        f16x8 v = *(const f16x8*)(V + key * 32 + k8);
#pragma unroll
        for (int e = 0; e < 8; ++e) VT[(k8 + e) * 264 + key] = v[e];
    }

    // Q fragment (B-operand of swapped QK^T), fold in softmax scale (exact pow2)
    f16x8 aq = *(const f16x8*)(Q + (qb + l15) * 32 + l4 * 8);
    aq = aq * (half_t)0.125f;

    __syncthreads();

    float m_run = -1e30f, s_run = 0.f;
    f32x4 acc_o[2] = {(f32x4){0.f, 0.f, 0.f, 0.f}, (f32x4){0.f, 0.f, 0.f, 0.f}};
    const f32x4 zero4 = (f32x4){0.f, 0.f, 0.f, 0.f};

    for (int kt = 0; kt < 4; ++kt) {
        // S^T tiles: A = K (rows=keys), B = Q^T. Lane: q=l15, key=16t+l4*4+r.
        f32x4 st[4];
#pragma unroll
        for (int t = 0; t < 4; ++t) {
            f16x8 ka = *(const f16x8*)(Kp + (kt * 64 + t * 16 + l15) * 32 + l4 * 8);
            st[t] = MFMA_F16(ka, aq, zero4);
        }

        // row max: 16 in-lane values, then combine the 4 l4 groups
        float mt = -1e30f;
#pragma unroll
        for (int t = 0; t < 4; ++t)
#pragma unroll
            for (int r = 0; r < 4; ++r) mt = fmaxf(mt, st[t][r]);
        mt = fmaxf(mt, __shfl_xor(mt, 16));
        mt = fmaxf(mt, __shfl_xor(mt, 32));

        float mn = fmaxf(m_run, mt);
        float corr = __expf(m_run - mn);
        m_run = mn;

        float p[4][4];
        float ps = 0.f;
#pragma unroll
        for (int t = 0; t < 4; ++t)
#pragma unroll
            for (int r = 0; r < 4; ++r) {
                float e = __expf(st[t][r] - mn);
                p[t][r] = e;
                ps += e;
            }
        ps += __shfl_xor(ps, 16);
        ps += __shfl_xor(ps, 32);
        s_run = s_run * corr + ps;

        // rescale O accumulator: acc row q = l4*4 + r -> corr from lane q
        float corrs[4];
#pragma unroll
        for (int r = 0; r < 4; ++r) corrs[r] = __shfl(corr, (l4 << 2) | r);
#pragma unroll
        for (int fo = 0; fo < 2; ++fo)
#pragma unroll
            for (int r = 0; r < 4; ++r) acc_o[fo][r] *= corrs[r];

        // P regroup -> A-frag (q=l15, 8 contiguous k) and PV MFMAs
#pragma unroll
        for (int c = 0; c < 2; ++c) {
            unsigned pk0[2], pk1[2];
#pragma unroll
            for (int rp = 0; rp < 2; ++rp) {
                pk0[rp] = pkrtz(p[2 * c][2 * rp], p[2 * c][2 * rp + 1]);
                pk1[rp] = pkrtz(p[2 * c + 1][2 * rp], p[2 * c + 1][2 * rp + 1]);
            }
            union { unsigned u[4]; f16x8 v; } au;
#pragma unroll
            for (int j = 0; j < 4; ++j) {
                int src = l15 + ((((l4 & 1) << 1) + (j >> 1)) << 4);
                unsigned g0 = (unsigned)__shfl((int)pk0[j & 1], src);
                unsigned g1 = (unsigned)__shfl((int)pk1[j & 1], src);
                au.u[j] = (l4 < 2) ? g0 : g1;
            }
#pragma unroll
            for (int fo = 0; fo < 2; ++fo) {
                f16x8 bv = *(const f16x8*)&VT[(fo * 16 + l15) * 264 + kt * 64 + c * 32 + l4 * 8];
                acc_o[fo] = MFMA_F16(au.v, bv, acc_o[fo]);
            }
        }
    }

    // finalize: O row q = l4*4+r needs 1/s_run from lane q
    float inv = 1.f / s_run;
    float sinv[4];
#pragma unroll
    for (int r = 0; r < 4; ++r) sinv[r] = __shfl(inv, (l4 << 2) | r);
#pragma unroll
    for (int fo = 0; fo < 2; ++fo)
#pragma unroll
        for (int r = 0; r < 4; ++r) {
            int grow = b * 4096 + blk * 256 + qb + l4 * 4 + r;
            o_ws[(size_t)grow * 256 + h * 32 + fo * 16 + l15] =
                (half_t)(acc_o[fo][r] * sinv[r]);
        }
}

// ---------------------------------------------------------------------------
extern "C" void kernel_launch(void* const* d_in, const int* in_sizes, int n_in,
                              void* d_out, int out_size, void* d_ws, size_t ws_size,
                              hipStream_t stream) {
    const float* x        = (const float*)d_in[0];
    const float* reduce_w = (const float*)d_in[1];
    const float* qkv_w    = (const float*)d_in[2];
    const float* proj_w   = (const float*)d_in[3];
    const float* proj_b   = (const float*)d_in[4];
    char* ws = (char*)d_ws;

    // ws layout (bytes):
    //   qkv_ws : 0          .. 25,165,824   (3 x 4,194,304 halves, q/k/v)
    //   xro    : 25,165,824 .. 33,554,432   (xr, later reused as o)
    //   rw_t   : 33,554,432 (+262,144)
    //   qw_t   : 33,816,576 (+393,216)
    //   pw_t   : 34,209,792 (+262,144)
    half_t* qkv_ws = (half_t*)ws;
    half_t* xro    = (half_t*)(ws + 25165824);
    half_t* rw_t   = (half_t*)(ws + 33554432);
    half_t* qw_t   = (half_t*)(ws + 33816576);
    half_t* pw_t   = (half_t*)(ws + 34209792);

    transpose_cvt<<<512, 256, 0, stream>>>(reduce_w, rw_t, 512, 256);
    transpose_cvt<<<768, 256, 0, stream>>>(qkv_w,   qw_t, 256, 768);
    transpose_cvt<<<512, 256, 0, stream>>>(proj_w,  pw_t, 256, 512);

    // xr = x @ reduce_w         (M=16384, N=256, K=512), fp32 A
    gemm_f16<0, true ><<<dim3(256, 1), 256, 0, stream>>>(x,   rw_t, xro,    nullptr, 512);
    // qkv = xr @ qkv_w          (M=16384, N=768, K=256), scatter epilogue
    gemm_f16<1, false><<<dim3(256, 3), 256, 0, stream>>>(xro, qw_t, qkv_ws, nullptr, 256);
    // block-diagonal attention  (2048 WGs = 512 blocks x 4 q-quadrants)
    attn_f16<<<2048, 256, 0, stream>>>(qkv_ws, xro);
    // out = o @ proj_w + proj_b (M=16384, N=512, K=256), fp32 out
    gemm_f16<2, false><<<dim3(256, 2), 256, 0, stream>>>(xro, pw_t, d_out,  proj_b, 256);
}

// Round 4
// 72.320 us; speedup vs baseline: 1.2958x; 1.1137x over previous
//
#include <hip/hip_runtime.h>
#include <hip/hip_fp16.h>

typedef _Float16 half_t;
typedef _Float16 f16x8 __attribute__((ext_vector_type(8)));
typedef __fp16 fp16x2 __attribute__((ext_vector_type(2)));
typedef float f32x4 __attribute__((ext_vector_type(4)));

#define MFMA_F16(a, b, c) __builtin_amdgcn_mfma_f32_16x16x32_f16((a), (b), (c), 0, 0, 0)

static __device__ inline unsigned pkrtz(float a, float b) {
    union { fp16x2 h; unsigned u; } c;
    c.h = __builtin_amdgcn_cvt_pkrtz(a, b);
    return c.u;
}

// ---------------------------------------------------------------------------
// One-shot weight prep: transpose+cvt all three weights; fold softmax scale
// (0.125) into the q-columns of qkv_w.
// ---------------------------------------------------------------------------
__global__ void prep_weights(const float* __restrict__ rw, const float* __restrict__ qw,
                             const float* __restrict__ pw, half_t* __restrict__ rw_t,
                             half_t* __restrict__ qw_t, half_t* __restrict__ pw_t) {
    int idx = blockIdx.x * 256 + threadIdx.x;
    if (idx < 131072) {                       // reduce_w: 512 x 256
        int r = idx >> 8, c = idx & 255;
        rw_t[c * 512 + r] = (half_t)rw[idx];
    } else if (idx < 327680) {                // qkv_w: 256 x 768
        int j = idx - 131072;
        int r = j / 768, c = j - r * 768;
        float v = qw[j];
        if (c < 256) v *= 0.125f;             // fold softmax scale into q
        qw_t[c * 256 + r] = (half_t)v;
    } else if (idx < 458752) {                // proj_w: 256 x 512
        int j = idx - 327680;
        int r = j >> 9, c = j & 511;
        pw_t[c * 256 + r] = (half_t)pw[j];
    }
}

// ---------------------------------------------------------------------------
// fp16 MFMA GEMM, reg-staged double-buffered:  D[M][N] = A[M][K] * Bt[N][K]^T
// BM=32*MI, BN=256, BK=64, 256 threads (4 waves, 2x2), wave tile (16*MI)x128.
// Pipeline: regs hold tile kt+1 while LDS holds tile kt.
// EPI 0: store half_t row-major ld=256 (xr)
// EPI 1: scatter q/k to [t][blk][key][dd], v to [2][blk][dd][key] (V^T)
// EPI 2: float out[grow*512+gcol] = acc + bias[gcol]
// ---------------------------------------------------------------------------
template <int EPI, bool AFP32, int MI>
__global__ __launch_bounds__(256) void gemm_f16(
    const void* __restrict__ Aptr, const half_t* __restrict__ Bt,
    void* __restrict__ Dst, const float* __restrict__ bias, int K) {
    constexpr int BM = 32 * MI;
    __shared__ __align__(16) char smem[(BM + 256) * 128];
    char* As = smem;
    char* Bs = smem + BM * 128;

    const int tid = threadIdx.x;
    const int lane = tid & 63, w = tid >> 6;
    const int l15 = lane & 15, l4 = lane >> 4;
    const int wrow = (w >> 1) * 16 * MI, wcol = (w & 1) * 128;
    const int bm0 = blockIdx.x * BM;
    const int bn0 = blockIdx.y * 256;

    f32x4 acc[MI][8];
#pragma unroll
    for (int i = 0; i < MI; ++i)
#pragma unroll
        for (int j = 0; j < 8; ++j) acc[i][j] = (f32x4){0.f, 0.f, 0.f, 0.f};

    const int nkt = K >> 6;
    f16x8 aReg[MI], bReg[8];

    auto load_tile = [&](int kt) {
#pragma unroll
        for (int i = 0; i < MI; ++i) {
            int c = tid + i * 256;
            int row = c >> 3, k0 = (c & 7) * 8;
            int gk = kt * 64 + k0;
            if (AFP32) {
                const float* Af = (const float*)Aptr + (size_t)(bm0 + row) * K + gk;
                float4 u0 = *(const float4*)Af;
                float4 u1 = *(const float4*)(Af + 4);
                f16x8 v;
                v[0] = (half_t)u0.x; v[1] = (half_t)u0.y;
                v[2] = (half_t)u0.z; v[3] = (half_t)u0.w;
                v[4] = (half_t)u1.x; v[5] = (half_t)u1.y;
                v[6] = (half_t)u1.z; v[7] = (half_t)u1.w;
                aReg[i] = v;
            } else {
                aReg[i] = *(const f16x8*)((const half_t*)Aptr + (size_t)(bm0 + row) * K + gk);
            }
        }
#pragma unroll
        for (int i = 0; i < 8; ++i) {
            int c = tid + i * 256;
            int row = c >> 3, k0 = (c & 7) * 8;
            bReg[i] = *(const f16x8*)(Bt + (size_t)(bn0 + row) * K + kt * 64 + k0);
        }
    };

    load_tile(0);
    for (int kt = 0; kt < nkt; ++kt) {
        __syncthreads();  // previous tile's readers done
#pragma unroll
        for (int i = 0; i < MI; ++i) {
            int c = tid + i * 256;
            int row = c >> 3, k0 = (c & 7) * 8;
            *(f16x8*)(As + row * 128 + ((k0 * 2) ^ ((row & 7) << 4))) = aReg[i];
        }
#pragma unroll
        for (int i = 0; i < 8; ++i) {
            int c = tid + i * 256;
            int row = c >> 3, k0 = (c & 7) * 8;
            *(f16x8*)(Bs + row * 128 + ((k0 * 2) ^ ((row & 7) << 4))) = bReg[i];
        }
        __syncthreads();
        if (kt + 1 < nkt) load_tile(kt + 1);  // prefetch under compute
#pragma unroll
        for (int ki = 0; ki < 2; ++ki) {
            int k0 = ki * 32 + l4 * 8;
            f16x8 af[MI], bfr[8];
#pragma unroll
            for (int mi = 0; mi < MI; ++mi) {
                int row = wrow + mi * 16 + l15;
                af[mi] = *(const f16x8*)(As + row * 128 + ((k0 * 2) ^ ((row & 7) << 4)));
            }
#pragma unroll
            for (int nj = 0; nj < 8; ++nj) {
                int row = wcol + nj * 16 + l15;
                bfr[nj] = *(const f16x8*)(Bs + row * 128 + ((k0 * 2) ^ ((row & 7) << 4)));
            }
#pragma unroll
            for (int mi = 0; mi < MI; ++mi)
#pragma unroll
                for (int nj = 0; nj < 8; ++nj)
                    acc[mi][nj] = MFMA_F16(af[mi], bfr[nj], acc[mi][nj]);
        }
    }

    // ---- epilogue ----
#pragma unroll
    for (int mi = 0; mi < MI; ++mi) {
#pragma unroll
        for (int nj = 0; nj < 8; ++nj) {
#pragma unroll
            for (int reg = 0; reg < 4; ++reg) {
                int grow = bm0 + wrow + mi * 16 + l4 * 4 + reg;
                int gcol = bn0 + wcol + nj * 16 + l15;
                float val = acc[mi][nj][reg];
                if (EPI == 0) {
                    ((half_t*)Dst)[(size_t)grow * 256 + gcol] = (half_t)val;
                } else if (EPI == 1) {
                    int t = gcol >> 8, h = (gcol >> 5) & 7, dd = gcol & 31;
                    int b = grow >> 12, n = grow & 4095;
                    int blk = n >> 8, r = n & 255;
                    size_t base = (size_t)t * 4194304 +
                                  (size_t)((((b << 3) + h) << 4) + blk) * 8192;
                    size_t idx = (t == 2) ? base + (size_t)dd * 256 + r     // V^T
                                          : base + (size_t)r * 32 + dd;
                    ((half_t*)Dst)[idx] = (half_t)val;
                } else {
                    ((float*)Dst)[(size_t)grow * 512 + gcol] = val + bias[gcol];
                }
            }
        }
    }
}

// ---------------------------------------------------------------------------
// Block-diagonal attention, swapped-QK^T, fully LDS-free / barrier-free.
// Grid 1024 = 512 blocks x 2 halves; WG = 4 independent waves; each wave
// owns 32 q rows (2 groups of 16). S^T = mfma(K, Q): lane holds P for
// q = lane&15 -> softmax in-lane + 2 shfl_xor. P repacked via cvt_pkrtz+shfl.
// V^T read straight from global (written transposed by the qkv GEMM).
// ---------------------------------------------------------------------------
__global__ __launch_bounds__(256, 4) void attn_f16(const half_t* __restrict__ qkv_ws,
                                                   half_t* __restrict__ o_ws) {
    const int bid = blockIdx.x;
    const int blkid = bid >> 1, hh = bid & 1;
    const int b = blkid >> 7, h = (blkid >> 4) & 7, blk = blkid & 15;
    const half_t* Q  = qkv_ws + (size_t)blkid * 8192;
    const half_t* Kp = qkv_ws + 4194304 + (size_t)blkid * 8192;
    const half_t* VT = qkv_ws + 8388608 + (size_t)blkid * 8192;  // [dd][key]

    const int tid = threadIdx.x, lane = tid & 63, w = tid >> 6;
    const int l15 = lane & 15, l4 = lane >> 4;
    const int qb = hh * 128 + w * 32;  // this wave's q-row base (32 rows)

    f16x8 aq[2];
    aq[0] = *(const f16x8*)(Q + (qb + l15) * 32 + l4 * 8);
    aq[1] = *(const f16x8*)(Q + (qb + 16 + l15) * 32 + l4 * 8);

    float m_run[2] = {-1e30f, -1e30f}, s_run[2] = {0.f, 0.f};
    f32x4 acc_o[2][2];
#pragma unroll
    for (int qg = 0; qg < 2; ++qg)
#pragma unroll
        for (int fo = 0; fo < 2; ++fo) acc_o[qg][fo] = (f32x4){0.f, 0.f, 0.f, 0.f};
    const f32x4 zero4 = (f32x4){0.f, 0.f, 0.f, 0.f};

    for (int kt = 0; kt < 4; ++kt) {
        f16x8 ka[4];
#pragma unroll
        for (int t = 0; t < 4; ++t)
            ka[t] = *(const f16x8*)(Kp + (kt * 64 + t * 16 + l15) * 32 + l4 * 8);
        f16x8 bv[2][2];
#pragma unroll
        for (int c = 0; c < 2; ++c)
#pragma unroll
            for (int fo = 0; fo < 2; ++fo)
                bv[c][fo] = *(const f16x8*)(VT + (fo * 16 + l15) * 256 + kt * 64 + c * 32 + l4 * 8);

#pragma unroll
        for (int qg = 0; qg < 2; ++qg) {
            // S^T: lane q=l15, key = kt*64 + t*16 + l4*4 + r
            f32x4 st[4];
#pragma unroll
            for (int t = 0; t < 4; ++t) st[t] = MFMA_F16(ka[t], aq[qg], zero4);

            float mt = -1e30f;
#pragma unroll
            for (int t = 0; t < 4; ++t)
#pragma unroll
                for (int r = 0; r < 4; ++r) mt = fmaxf(mt, st[t][r]);
            mt = fmaxf(mt, __shfl_xor(mt, 16));
            mt = fmaxf(mt, __shfl_xor(mt, 32));

            float mn = fmaxf(m_run[qg], mt);
            float corr = __expf(m_run[qg] - mn);
            m_run[qg] = mn;

            float p[4][4];
            float ps = 0.f;
#pragma unroll
            for (int t = 0; t < 4; ++t)
#pragma unroll
                for (int r = 0; r < 4; ++r) {
                    float e = __expf(st[t][r] - mn);
                    p[t][r] = e;
                    ps += e;
                }
            ps += __shfl_xor(ps, 16);
            ps += __shfl_xor(ps, 32);
            s_run[qg] = s_run[qg] * corr + ps;

            float corrs[4];
#pragma unroll
            for (int r = 0; r < 4; ++r) corrs[r] = __shfl(corr, (l4 << 2) | r);
#pragma unroll
            for (int fo = 0; fo < 2; ++fo)
#pragma unroll
                for (int r = 0; r < 4; ++r) acc_o[qg][fo][r] *= corrs[r];

            // P regroup -> A-frag (q=l15, 8 contiguous k), PV MFMAs
#pragma unroll
            for (int c = 0; c < 2; ++c) {
                unsigned pk0[2], pk1[2];
#pragma unroll
                for (int rp = 0; rp < 2; ++rp) {
                    pk0[rp] = pkrtz(p[2 * c][2 * rp], p[2 * c][2 * rp + 1]);
                    pk1[rp] = pkrtz(p[2 * c + 1][2 * rp], p[2 * c + 1][2 * rp + 1]);
                }
                union { unsigned u[4]; f16x8 v; } au;
#pragma unroll
                for (int j = 0; j < 4; ++j) {
                    int src = l15 + ((((l4 & 1) << 1) + (j >> 1)) << 4);
                    unsigned g0 = (unsigned)__shfl((int)pk0[j & 1], src);
                    unsigned g1 = (unsigned)__shfl((int)pk1[j & 1], src);
                    au.u[j] = (l4 < 2) ? g0 : g1;
                }
#pragma unroll
                for (int fo = 0; fo < 2; ++fo)
                    acc_o[qg][fo] = MFMA_F16(au.v, bv[c][fo], acc_o[qg][fo]);
            }
        }
    }

    // finalize + store o (head-major layout [row][h*32+dd])
#pragma unroll
    for (int qg = 0; qg < 2; ++qg) {
        float inv = 1.f / s_run[qg];
        float sinv[4];
#pragma unroll
        for (int r = 0; r < 4; ++r) sinv[r] = __shfl(inv, (l4 << 2) | r);
#pragma unroll
        for (int fo = 0; fo < 2; ++fo)
#pragma unroll
            for (int r = 0; r < 4; ++r) {
                int grow = b * 4096 + blk * 256 + qb + qg * 16 + l4 * 4 + r;
                o_ws[(size_t)grow * 256 + h * 32 + fo * 16 + l15] =
                    (half_t)(acc_o[qg][fo][r] * sinv[r]);
            }
    }
}

// ---------------------------------------------------------------------------
extern "C" void kernel_launch(void* const* d_in, const int* in_sizes, int n_in,
                              void* d_out, int out_size, void* d_ws, size_t ws_size,
                              hipStream_t stream) {
    const float* x        = (const float*)d_in[0];
    const float* reduce_w = (const float*)d_in[1];
    const float* qkv_w    = (const float*)d_in[2];
    const float* proj_w   = (const float*)d_in[3];
    const float* proj_b   = (const float*)d_in[4];
    char* ws = (char*)d_ws;

    half_t* qkv_ws = (half_t*)ws;                      // 3 x 4,194,304 halves
    half_t* xro    = (half_t*)(ws + 25165824);         // xr, later o
    half_t* rw_t   = (half_t*)(ws + 33554432);
    half_t* qw_t   = (half_t*)(ws + 33816576);
    half_t* pw_t   = (half_t*)(ws + 34209792);

    prep_weights<<<1792, 256, 0, stream>>>(reduce_w, qkv_w, proj_w, rw_t, qw_t, pw_t);

    // xr = x @ reduce_w         (M=16384, N=256, K=512), fp32 A, BM=32
    gemm_f16<0, true , 1><<<dim3(512, 1), 256, 0, stream>>>(x,   rw_t, xro,    nullptr, 512);
    // qkv = xr @ qkv_w          (M=16384, N=768, K=256), scatter epi (V transposed)
    gemm_f16<1, false, 2><<<dim3(256, 3), 256, 0, stream>>>(xro, qw_t, qkv_ws, nullptr, 256);
    // block-diagonal attention  (1024 WGs = 512 blocks x 2 halves), LDS-free
    attn_f16<<<1024, 256, 0, stream>>>(qkv_ws, xro);
    // out = o @ proj_w + proj_b (M=16384, N=512, K=256), fp32 out
    gemm_f16<2, false, 2><<<dim3(256, 2), 256, 0, stream>>>(xro, pw_t, d_out,  proj_b, 256);
}